// Round 13
// baseline (337.430 us; speedup 1.0000x reference)
//
#include <hip/hip_runtime.h>
#include <hip/hip_bf16.h>

// GCN 2-layer: N=100000 nodes, E=1600000 edges, F=64, H=64, C=16.
// GCNConv: out[v] = dinv[v]*( g[v] + sum_{u->v} g[u] ) + b,  g[u] = (x[u]@W)*dinv[u]
// Round 13: g1 stored UNSCALED bf16(x@W1); dinv[u] applied in agg1 (broadcast
// 4B load per edge).  This breaks gemm1's dependency on scanwrite, making the
// degrank+gemm1 fusion legal (R9's bug).  Fusion is safe here unlike R10/R11:
// no launch_bounds cap (no spill), and degrank is occupancy-INSENSITIVE
// (atomic ceiling flat 68-69.5us across 8-14 waves/CU, R7/R8/R12).
// rank[] aliases h1p[]; bnparam inlined into bn_gemm2.

#define G1_BLOCKS 512

union bfpack4 { ushort4 u; __hip_bfloat16 h[4]; };

// blocks [0, drBlocks): degrank (atomic-pipe-bound, flat vs occupancy)
// blocks [drBlocks, drBlocks+G1_BLOCKS): persistent gemm1, g1 = bf16(x@W1) UNSCALED
__global__ __launch_bounds__(256) void k_build(const int* __restrict__ dst, int E,
                                               unsigned* __restrict__ deg,
                                               unsigned* __restrict__ rank,
                                               const float* __restrict__ x,
                                               const float* __restrict__ W1, int n,
                                               __hip_bfloat16* __restrict__ g1,
                                               int drBlocks) {
    __shared__ __align__(16) float w1s[64 * 64];   // [k][c], 16KB
    __shared__ __align__(16) float xs[64 * 68];    // [k][node], pad 68, 17.4KB
    int tid = threadIdx.x;

    if (blockIdx.x < drBlocks) {
        // ---------------- degrank body ----------------
        int gid = blockIdx.x * 256 + tid;
        int stride = drBlocks * 256;
        int nquad = E >> 2;
        int npair = nquad >> 1;          // 8 edges per thread-iteration
        for (int p = gid; p < npair; p += stride) {
            int4 da = *(const int4*)(dst + (size_t)p * 4);
            int4 db = *(const int4*)(dst + (size_t)(npair + p) * 4);
            unsigned a0 = atomicAdd(&deg[da.x], 1u);
            unsigned a1 = atomicAdd(&deg[da.y], 1u);
            unsigned a2 = atomicAdd(&deg[da.z], 1u);
            unsigned a3 = atomicAdd(&deg[da.w], 1u);
            unsigned b0 = atomicAdd(&deg[db.x], 1u);
            unsigned b1 = atomicAdd(&deg[db.y], 1u);
            unsigned b2 = atomicAdd(&deg[db.z], 1u);
            unsigned b3 = atomicAdd(&deg[db.w], 1u);
            *(uint4*)(rank + (size_t)p * 4) = make_uint4(a0, a1, a2, a3);
            *(uint4*)(rank + (size_t)(npair + p) * 4) = make_uint4(b0, b1, b2, b3);
        }
        for (int t = npair * 8 + gid; t < E; t += stride)
            rank[t] = atomicAdd(&deg[dst[t]], 1u);
        return;
    }

    // ------------- gemm1 body (persistent, 64-node tiles, 4x4 reg block) -------------
    int bid = blockIdx.x - drBlocks;
    int w = tid >> 6, lane = tid & 63;
    int cg = lane & 15, ng = lane >> 4;   // channels cg*4..+3, nodes w*16+ng*4..+3

    for (int r = 0; r < 4; ++r) {
        int idx = r * 256 + tid;
        *(float4*)&w1s[idx * 4] = *(const float4*)&W1[idx * 4];
    }

    int ntiles = (n + 63) >> 6;
    for (int tile = bid; tile < ntiles; tile += G1_BLOCKS) {
        int v0 = tile << 6;
        __syncthreads();   // protect xs from previous iteration's readers
        for (int r = 0; r < 4; ++r) {
            int flat = r * 1024 + tid * 4;
            int node = flat >> 6, k0 = flat & 63;
            int v = v0 + node;
            float4 xv = (v < n) ? *(const float4*)&x[(size_t)v * 64 + k0]
                                : make_float4(0.f, 0.f, 0.f, 0.f);
            xs[(k0 + 0) * 68 + node] = xv.x;
            xs[(k0 + 1) * 68 + node] = xv.y;
            xs[(k0 + 2) * 68 + node] = xv.z;
            xs[(k0 + 3) * 68 + node] = xv.w;
        }
        __syncthreads();

        float4 acc[4] = {{0,0,0,0},{0,0,0,0},{0,0,0,0},{0,0,0,0}};
        int nbase = w * 16 + ng * 4;
#pragma unroll
        for (int k = 0; k < 64; ++k) {
            float4 xv = *(float4*)&xs[k * 68 + nbase];
            float4 wv = *(float4*)&w1s[k * 64 + cg * 4];
            acc[0].x += xv.x * wv.x; acc[0].y += xv.x * wv.y;
            acc[0].z += xv.x * wv.z; acc[0].w += xv.x * wv.w;
            acc[1].x += xv.y * wv.x; acc[1].y += xv.y * wv.y;
            acc[1].z += xv.y * wv.z; acc[1].w += xv.y * wv.w;
            acc[2].x += xv.z * wv.x; acc[2].y += xv.z * wv.y;
            acc[2].z += xv.z * wv.z; acc[2].w += xv.z * wv.w;
            acc[3].x += xv.w * wv.x; acc[3].y += xv.w * wv.y;
            acc[3].z += xv.w * wv.z; acc[3].w += xv.w * wv.w;
        }
        for (int a = 0; a < 4; ++a) {
            int v = v0 + nbase + a;
            if (v < n) {
                bfpack4 pk;   // UNSCALED: dinv applied in agg1
                pk.h[0] = __float2bfloat16(acc[a].x);
                pk.h[1] = __float2bfloat16(acc[a].y);
                pk.h[2] = __float2bfloat16(acc[a].z);
                pk.h[3] = __float2bfloat16(acc[a].w);
                *(ushort4*)&g1[(size_t)v * 64 + cg * 4] = pk.u;
            }
        }
    }
}

// ---- 3-phase multi-block exclusive scan over deg (1024 elems/block) ----
__global__ __launch_bounds__(256) void k_bsum(const unsigned* __restrict__ deg, int n,
                                              unsigned* __restrict__ bsum) {
    __shared__ unsigned lds[256];
    int tid = threadIdx.x;
    int base = blockIdx.x * 1024 + tid * 4;
    unsigned s = 0;
    if (base + 3 < n) {
        uint4 v = *(const uint4*)(deg + base);
        s = v.x + v.y + v.z + v.w;
    } else {
        for (int i = 0; i < 4; ++i) if (base + i < n) s += deg[base + i];
    }
    lds[tid] = s;
    __syncthreads();
    for (int off = 128; off > 0; off >>= 1) {
        if (tid < off) lds[tid] += lds[tid + off];
        __syncthreads();
    }
    if (tid == 0) bsum[blockIdx.x] = lds[0];
}

__global__ void k_bscan(unsigned* __restrict__ bsum, int nbs) {
    __shared__ unsigned lds[256];
    int tid = threadIdx.x;
    unsigned v = (tid < nbs) ? bsum[tid] : 0u;
    lds[tid] = v;
    __syncthreads();
    for (int off = 1; off < 256; off <<= 1) {
        unsigned t = (tid >= off) ? lds[tid - off] : 0u;
        __syncthreads();
        lds[tid] += t;
        __syncthreads();
    }
    if (tid < nbs) bsum[tid] = lds[tid] - v;  // exclusive
}

__global__ __launch_bounds__(256) void k_scanwrite(const unsigned* __restrict__ deg,
                                                   const unsigned* __restrict__ bsum, int n,
                                                   unsigned* __restrict__ row_start,
                                                   float* __restrict__ dinv) {
    __shared__ unsigned lds[256];
    int tid = threadIdx.x;
    int base = blockIdx.x * 1024 + tid * 4;
    unsigned d0 = 0, d1 = 0, d2 = 0, d3 = 0;
    bool full = (base + 3 < n);
    if (full) {
        uint4 v = *(const uint4*)(deg + base);
        d0 = v.x; d1 = v.y; d2 = v.z; d3 = v.w;
    } else {
        if (base + 0 < n) d0 = deg[base + 0];
        if (base + 1 < n) d1 = deg[base + 1];
        if (base + 2 < n) d2 = deg[base + 2];
    }
    unsigned s = d0 + d1 + d2 + d3;
    lds[tid] = s;
    __syncthreads();
    for (int off = 1; off < 256; off <<= 1) {
        unsigned t = (tid >= off) ? lds[tid - off] : 0u;
        __syncthreads();
        lds[tid] += t;
        __syncthreads();
    }
    unsigned run = bsum[blockIdx.x] + lds[tid] - s;  // exclusive prefix at base
    unsigned r0 = run, r1 = r0 + d0, r2 = r1 + d1, r3 = r2 + d2;
    if (full) {
        *(uint4*)(row_start + base) = make_uint4(r0, r1, r2, r3);
        *(float4*)(dinv + base) = make_float4(rsqrtf((float)(d0 + 1u)), rsqrtf((float)(d1 + 1u)),
                                              rsqrtf((float)(d2 + 1u)), rsqrtf((float)(d3 + 1u)));
    } else {
        unsigned r[4] = {r0, r1, r2, r3};
        unsigned d[4] = {d0, d1, d2, d3};
        for (int i = 0; i < 4; ++i)
            if (base + i < n) {
                row_start[base + i] = r[i];
                dinv[base + i] = rsqrtf((float)(d[i] + 1u));
            }
    }
}

// No atomics: absolute slot = row_start[dst] + rank.  8 edges per iteration.
__global__ void k_fillr(const int* __restrict__ src, const int* __restrict__ dst,
                        const unsigned* __restrict__ rank, int E,
                        const unsigned* __restrict__ row_start,
                        unsigned* __restrict__ csr_src) {
    int gid = blockIdx.x * blockDim.x + threadIdx.x;
    int stride = gridDim.x * blockDim.x;
    int nquad = E >> 2;
    int npair = nquad >> 1;
    for (int p = gid; p < npair; p += stride) {
        int4 sa = *(const int4*)(src + (size_t)p * 4);
        int4 da = *(const int4*)(dst + (size_t)p * 4);
        uint4 ra = *(const uint4*)(rank + (size_t)p * 4);
        int4 sb = *(const int4*)(src + (size_t)(npair + p) * 4);
        int4 db = *(const int4*)(dst + (size_t)(npair + p) * 4);
        uint4 rb = *(const uint4*)(rank + (size_t)(npair + p) * 4);
        unsigned q0 = row_start[da.x];
        unsigned q1 = row_start[da.y];
        unsigned q2 = row_start[da.z];
        unsigned q3 = row_start[da.w];
        unsigned q4 = row_start[db.x];
        unsigned q5 = row_start[db.y];
        unsigned q6 = row_start[db.z];
        unsigned q7 = row_start[db.w];
        csr_src[q0 + ra.x] = (unsigned)sa.x;
        csr_src[q1 + ra.y] = (unsigned)sa.y;
        csr_src[q2 + ra.z] = (unsigned)sa.z;
        csr_src[q3 + ra.w] = (unsigned)sa.w;
        csr_src[q4 + rb.x] = (unsigned)sb.x;
        csr_src[q5 + rb.y] = (unsigned)sb.y;
        csr_src[q6 + rb.z] = (unsigned)sb.z;
        csr_src[q7 + rb.w] = (unsigned)sb.w;
    }
    for (int t = npair * 8 + gid; t < E; t += stride)
        csr_src[row_start[dst[t]] + rank[t]] = (unsigned)src[t];
}

// h1p[v] = dinv[v]*( g1[v]*dinv[v] ... wait, see formula ) -- with UNSCALED g1:
// h1p[v] = dinv[v]*( g1[v]*dinv[v] + sum_u g1[u]*dinv[u] ) + b1
// dinv[u] is wave-uniform per gathered row -> broadcast 4B load.
__global__ __launch_bounds__(256) void k_agg1(const __hip_bfloat16* __restrict__ g1,
                                              const unsigned* __restrict__ row_start,
                                              const unsigned* __restrict__ deg,
                                              const unsigned* __restrict__ csr_src,
                                              const float* __restrict__ dinv,
                                              const float* __restrict__ b1, int n,
                                              float* __restrict__ h1p,
                                              double* __restrict__ bn_part) {
    int tid = threadIdx.x;
    int lane = tid & 63, w = tid >> 6;
    int waveId = blockIdx.x * 4 + w;
    int nWaves = gridDim.x * 4;
    double lsum = 0.0, lsq = 0.0;
    float bb = b1[lane];
    for (int v = waveId; v < n; v += nWaves) {
        float dv = dinv[v];
        unsigned start = row_start[v], cnt = deg[v];
        float acc = __bfloat162float(g1[(size_t)v * 64 + lane]) * dv;   // self-loop
        unsigned j = 0;
        for (; j + 8 <= cnt; j += 8) {   // 8 independent 128B gathers in flight
            unsigned u0 = csr_src[start + j + 0];
            unsigned u1 = csr_src[start + j + 1];
            unsigned u2 = csr_src[start + j + 2];
            unsigned u3 = csr_src[start + j + 3];
            unsigned u4 = csr_src[start + j + 4];
            unsigned u5 = csr_src[start + j + 5];
            unsigned u6 = csr_src[start + j + 6];
            unsigned u7 = csr_src[start + j + 7];
            float d0 = dinv[u0], d1 = dinv[u1], d2 = dinv[u2], d3 = dinv[u3];
            float d4 = dinv[u4], d5 = dinv[u5], d6 = dinv[u6], d7 = dinv[u7];
            float f0 = __bfloat162float(g1[(size_t)u0 * 64 + lane]);
            float f1 = __bfloat162float(g1[(size_t)u1 * 64 + lane]);
            float f2 = __bfloat162float(g1[(size_t)u2 * 64 + lane]);
            float f3 = __bfloat162float(g1[(size_t)u3 * 64 + lane]);
            float f4 = __bfloat162float(g1[(size_t)u4 * 64 + lane]);
            float f5 = __bfloat162float(g1[(size_t)u5 * 64 + lane]);
            float f6 = __bfloat162float(g1[(size_t)u6 * 64 + lane]);
            float f7 = __bfloat162float(g1[(size_t)u7 * 64 + lane]);
            acc += ((f0 * d0 + f1 * d1) + (f2 * d2 + f3 * d3))
                 + ((f4 * d4 + f5 * d5) + (f6 * d6 + f7 * d7));
        }
        for (; j + 4 <= cnt; j += 4) {
            unsigned u0 = csr_src[start + j + 0];
            unsigned u1 = csr_src[start + j + 1];
            unsigned u2 = csr_src[start + j + 2];
            unsigned u3 = csr_src[start + j + 3];
            float d0 = dinv[u0], d1 = dinv[u1], d2 = dinv[u2], d3 = dinv[u3];
            float f0 = __bfloat162float(g1[(size_t)u0 * 64 + lane]);
            float f1 = __bfloat162float(g1[(size_t)u1 * 64 + lane]);
            float f2 = __bfloat162float(g1[(size_t)u2 * 64 + lane]);
            float f3 = __bfloat162float(g1[(size_t)u3 * 64 + lane]);
            acc += (f0 * d0 + f1 * d1) + (f2 * d2 + f3 * d3);
        }
        for (; j < cnt; ++j) {
            unsigned u = csr_src[start + j];
            acc += __bfloat162float(g1[(size_t)u * 64 + lane]) * dinv[u];
        }
        float val = dv * acc + bb;
        h1p[(size_t)v * 64 + lane] = val;
        lsum += (double)val;
        lsq  += (double)val * (double)val;
    }
    __shared__ double red[4][64][2];
    red[w][lane][0] = lsum;
    red[w][lane][1] = lsq;
    __syncthreads();
    if (tid < 64) {
        double s = red[0][tid][0] + red[1][tid][0] + red[2][tid][0] + red[3][tid][0];
        double q = red[0][tid][1] + red[1][tid][1] + red[2][tid][1] + red[3][tid][1];
        double* p = bn_part + (size_t)(blockIdx.x & 7) * 128;  // 8-way sharded
        atomicAdd(&p[tid], s);
        atomicAdd(&p[64 + tid], q);
    }
}

// BN params recomputed per block (saves a launch); y = relu(h1p*sc+sh);
// g2[v] = bf16( (y[v]@W2) * dinv[v] ) -- persistent, 64-node tiles
__global__ __launch_bounds__(256) void k_bn_gemm2(const float* __restrict__ h1p,
                                                  const float* __restrict__ W2,
                                                  const double* __restrict__ bn_part,
                                                  const float* __restrict__ gamma,
                                                  const float* __restrict__ beta,
                                                  const float* __restrict__ dinv, int n,
                                                  __hip_bfloat16* __restrict__ g2) {
    __shared__ __align__(16) float w2s[64 * 16];   // [k][c], 4KB
    __shared__ __align__(16) float ys[64 * 68];    // [k][node], 17.4KB
    __shared__ float bnsc[64], bnsh[64];
    int tid = threadIdx.x;
    int w = tid >> 6, lane = tid & 63;
    int cg = lane & 3, ng = lane >> 2;   // channels cg*4..+3, node w*16+ng

    *(float4*)&w2s[tid * 4] = *(const float4*)&W2[tid * 4];   // 256*4 = 1024 exactly
    if (tid < 64) {
        double s = 0.0, q = 0.0;
        for (int p = 0; p < 8; ++p) {
            s += bn_part[p * 128 + tid];
            q += bn_part[p * 128 + 64 + tid];
        }
        double mean = s / n;
        double var = q / n - mean * mean;
        if (var < 0.0) var = 0.0;
        float scale = gamma[tid] * (float)(1.0 / sqrt(var + 1e-5));
        bnsc[tid] = scale;
        bnsh[tid] = beta[tid] - (float)mean * scale;
    }

    int ntiles = (n + 63) >> 6;
    for (int tile = blockIdx.x; tile < ntiles; tile += gridDim.x) {
        int v0 = tile << 6;
        __syncthreads();
        for (int r = 0; r < 4; ++r) {
            int flat = r * 1024 + tid * 4;
            int node = flat >> 6, k0 = flat & 63;
            int v = v0 + node;
            float4 hv = (v < n) ? *(const float4*)&h1p[(size_t)v * 64 + k0]
                                : make_float4(0.f, 0.f, 0.f, 0.f);
            ys[(k0 + 0) * 68 + node] = fmaxf(hv.x * bnsc[k0 + 0] + bnsh[k0 + 0], 0.f);
            ys[(k0 + 1) * 68 + node] = fmaxf(hv.y * bnsc[k0 + 1] + bnsh[k0 + 1], 0.f);
            ys[(k0 + 2) * 68 + node] = fmaxf(hv.z * bnsc[k0 + 2] + bnsh[k0 + 2], 0.f);
            ys[(k0 + 3) * 68 + node] = fmaxf(hv.w * bnsc[k0 + 3] + bnsh[k0 + 3], 0.f);
        }
        __syncthreads();

        float4 acc = {0, 0, 0, 0};
        int node = w * 16 + ng;
#pragma unroll
        for (int k = 0; k < 64; ++k) {
            float xv = ys[k * 68 + node];
            float4 wv = *(float4*)&w2s[k * 16 + cg * 4];
            acc.x += xv * wv.x; acc.y += xv * wv.y;
            acc.z += xv * wv.z; acc.w += xv * wv.w;
        }
        int v = v0 + node;
        if (v < n) {
            float dv = dinv[v];
            bfpack4 pk;
            pk.h[0] = __float2bfloat16(acc.x * dv);
            pk.h[1] = __float2bfloat16(acc.y * dv);
            pk.h[2] = __float2bfloat16(acc.z * dv);
            pk.h[3] = __float2bfloat16(acc.w * dv);
            *(ushort4*)&g2[(size_t)v * 16 + cg * 4] = pk.u;
        }
    }
}

// out[v] = dinv[v]*(g2[v] + sum_{u->v} g2[u]) + b2   (C=16; 16-lane groups)
__global__ __launch_bounds__(256) void k_agg2(const __hip_bfloat16* __restrict__ g2,
                                              const unsigned* __restrict__ row_start,
                                              const unsigned* __restrict__ deg,
                                              const unsigned* __restrict__ csr_src,
                                              const float* __restrict__ dinv,
                                              const float* __restrict__ b2, int n,
                                              float* __restrict__ out) {
    int tid = threadIdx.x;
    int lane = tid & 63, w = tid >> 6;
    int c = lane & 15, jg = lane >> 4;
    int waveId = blockIdx.x * 4 + w;
    int nWaves = gridDim.x * 4;
    for (int v = waveId; v < n; v += nWaves) {
        unsigned start = row_start[v], cnt = deg[v];
        float acc = (jg == 0) ? __bfloat162float(g2[(size_t)v * 16 + c]) : 0.f;
        unsigned j = jg;
        for (; j + 16 <= cnt; j += 16) {   // 4 lines in flight per group
            unsigned u0 = csr_src[start + j];
            unsigned u1 = csr_src[start + j + 4];
            unsigned u2 = csr_src[start + j + 8];
            unsigned u3 = csr_src[start + j + 12];
            float f0 = __bfloat162float(g2[(size_t)u0 * 16 + c]);
            float f1 = __bfloat162float(g2[(size_t)u1 * 16 + c]);
            float f2 = __bfloat162float(g2[(size_t)u2 * 16 + c]);
            float f3 = __bfloat162float(g2[(size_t)u3 * 16 + c]);
            acc += (f0 + f1) + (f2 + f3);
        }
        for (; j + 8 <= cnt; j += 8) {
            unsigned u0 = csr_src[start + j];
            unsigned u1 = csr_src[start + j + 4];
            float f0 = __bfloat162float(g2[(size_t)u0 * 16 + c]);
            float f1 = __bfloat162float(g2[(size_t)u1 * 16 + c]);
            acc += f0 + f1;
        }
        for (; j < cnt; j += 4) {
            unsigned u = csr_src[start + j];
            acc += __bfloat162float(g2[(size_t)u * 16 + c]);
        }
        acc += __shfl_xor(acc, 16, 64);
        acc += __shfl_xor(acc, 32, 64);
        if (jg == 0) out[(size_t)v * 16 + c] = dinv[v] * acc + b2[c];
    }
}

extern "C" void kernel_launch(void* const* d_in, const int* in_sizes, int n_in,
                              void* d_out, int out_size, void* d_ws, size_t ws_size,
                              hipStream_t stream) {
    const float* x     = (const float*)d_in[0];
    const int*   ei    = (const int*)d_in[1];
    const float* W1    = (const float*)d_in[2];
    const float* b1    = (const float*)d_in[3];
    const float* gamma = (const float*)d_in[4];
    const float* beta  = (const float*)d_in[5];
    const float* W2    = (const float*)d_in[6];
    const float* b2    = (const float*)d_in[7];
    float* out = (float*)d_out;

    int n = in_sizes[0] / 64;
    int E = in_sizes[1] / 2;
    const int* esrc = ei;
    const int* edst = ei + E;

    char* ws = (char*)d_ws;
    size_t off = 0;
    auto alloc = [&](size_t bytes) {
        size_t o = off;
        off += (bytes + 255) & ~(size_t)255;
        return o;
    };
    unsigned* deg       = (unsigned*)(ws + alloc((size_t)n * 4));
    unsigned* row_start = (unsigned*)(ws + alloc((size_t)n * 4));
    float*    dinv      = (float*)(ws + alloc((size_t)n * 4));
    unsigned* csr_src   = (unsigned*)(ws + alloc((size_t)E * 4));
    __hip_bfloat16* g1  = (__hip_bfloat16*)(ws + alloc((size_t)n * 64 * 2));
    // union region: rank (E*4, dead after k_fillr) aliases h1p (n*64*4, born in k_agg1)
    size_t uoff = alloc((((size_t)E * 4) > ((size_t)n * 64 * 4)) ? (size_t)E * 4
                                                                 : (size_t)n * 64 * 4);
    unsigned* rank      = (unsigned*)(ws + uoff);
    float*    h1p       = (float*)(ws + uoff);
    __hip_bfloat16* g2  = (__hip_bfloat16*)(ws + alloc((size_t)n * 16 * 2));
    double*   bn_part   = (double*)(ws + alloc(8 * 128 * 8));
    unsigned* bsum      = (unsigned*)(ws + alloc(1024 * 4));

    hipMemsetAsync(deg, 0, (size_t)n * 4, stream);
    hipMemsetAsync(bn_part, 0, 8 * 128 * 8, stream);

    int nbs = (n + 1023) / 1024;   // 98 for n=100000 (must be <= 256)
    int npair = (E >> 2) >> 1;
    int drBlocks = (npair + 255) / 256;   // 782: one 8-edge pack per thread

    k_build<<<drBlocks + G1_BLOCKS, 256, 0, stream>>>(edst, E, deg, rank,
                                                      x, W1, n, g1, drBlocks);
    k_bsum<<<nbs, 256, 0, stream>>>(deg, n, bsum);
    k_bscan<<<1, 256, 0, stream>>>(bsum, nbs);
    k_scanwrite<<<nbs, 256, 0, stream>>>(deg, bsum, n, row_start, dinv);
    k_fillr<<<1024, 256, 0, stream>>>(esrc, edst, rank, E, row_start, csr_src);
    k_agg1<<<2048, 256, 0, stream>>>(g1, row_start, deg, csr_src, dinv, b1, n, h1p, bn_part);
    k_bn_gemm2<<<512, 256, 0, stream>>>(h1p, W2, bn_part, gamma, beta, dinv, n, g2);
    k_agg2<<<2048, 256, 0, stream>>>(g2, row_start, deg, csr_src, dinv, b2, n, out);
}

// Round 14
// 332.134 us; speedup vs baseline: 1.0159x; 1.0159x over previous
//
#include <hip/hip_runtime.h>
#include <hip/hip_bf16.h>

// GCN 2-layer: N=100000 nodes, E=1600000 edges, F=64, H=64, C=16.
// GCNConv: out[v] = dinv[v]*( g[v] + sum_{u->v} g[u] ) + b,  g[u] = (x[u]@W)*dinv[u]
// g1/g2 stored bf16; accumulation f32.  CSR build via rank = atomicAdd return.
// MEASURED WALLS (do not re-attempt):
//  - degrank: device-scope atomic-RMW ceiling ~23G/s, flat 68-69.5us across
//    8-14 waves/CU (R7/R8/R12).  Below ~8 waves/CU it COLLAPSES (R13: 10%
//    occupancy -> ~105us).  Fusing anything register-hungry with it loses.
//  - fillr+gemm1 fusion: branch-max VGPR kills scatter occupancy (R10);
//    launch_bounds cap spills gemm1 (R11: 1.55GB scratch traffic, 638us).
// Round 14: R12 structure + k_bscan eliminated (scanwrite computes its own
// block prefix: nbs=98<=256, one 256-wide LDS reduce per block).

union bfpack4 { ushort4 u; __hip_bfloat16 h[4]; };

__global__ void k_degrank(const int* __restrict__ dst, int E, unsigned* __restrict__ deg,
                          unsigned* __restrict__ rank) {
    int gid = blockIdx.x * blockDim.x + threadIdx.x;
    int stride = gridDim.x * blockDim.x;
    int nquad = E >> 2;
    int npair = nquad >> 1;          // 8 edges per thread-iteration
    for (int p = gid; p < npair; p += stride) {
        int4 da = *(const int4*)(dst + (size_t)p * 4);
        int4 db = *(const int4*)(dst + (size_t)(npair + p) * 4);
        unsigned a0 = atomicAdd(&deg[da.x], 1u);
        unsigned a1 = atomicAdd(&deg[da.y], 1u);
        unsigned a2 = atomicAdd(&deg[da.z], 1u);
        unsigned a3 = atomicAdd(&deg[da.w], 1u);
        unsigned b0 = atomicAdd(&deg[db.x], 1u);
        unsigned b1 = atomicAdd(&deg[db.y], 1u);
        unsigned b2 = atomicAdd(&deg[db.z], 1u);
        unsigned b3 = atomicAdd(&deg[db.w], 1u);
        *(uint4*)(rank + (size_t)p * 4) = make_uint4(a0, a1, a2, a3);
        *(uint4*)(rank + (size_t)(npair + p) * 4) = make_uint4(b0, b1, b2, b3);
    }
    for (int t = npair * 8 + gid; t < E; t += stride)
        rank[t] = atomicAdd(&deg[dst[t]], 1u);
}

// ---- scan phase 1: per-block sums of deg (1024 elems/block) ----
__global__ __launch_bounds__(256) void k_bsum(const unsigned* __restrict__ deg, int n,
                                              unsigned* __restrict__ bsum) {
    __shared__ unsigned lds[256];
    int tid = threadIdx.x;
    int base = blockIdx.x * 1024 + tid * 4;
    unsigned s = 0;
    if (base + 3 < n) {
        uint4 v = *(const uint4*)(deg + base);
        s = v.x + v.y + v.z + v.w;
    } else {
        for (int i = 0; i < 4; ++i) if (base + i < n) s += deg[base + i];
    }
    lds[tid] = s;
    __syncthreads();
    for (int off = 128; off > 0; off >>= 1) {
        if (tid < off) lds[tid] += lds[tid + off];
        __syncthreads();
    }
    if (tid == 0) bsum[blockIdx.x] = lds[0];
}

// ---- scan phase 2: block prefix computed in-kernel (bsum is RAW sums;
// nbs <= 256, so a 256-wide reduce over bsum[0..blockIdx.x) suffices) ----
__global__ __launch_bounds__(256) void k_scanwrite(const unsigned* __restrict__ deg,
                                                   const unsigned* __restrict__ bsum, int nbs,
                                                   int n,
                                                   unsigned* __restrict__ row_start,
                                                   float* __restrict__ dinv) {
    __shared__ unsigned lds[256];
    __shared__ unsigned block_base;
    int tid = threadIdx.x;

    // exclusive prefix of raw block sums: sum of bsum[tid] for tid < blockIdx.x
    unsigned bv = (tid < (int)blockIdx.x && tid < nbs) ? bsum[tid] : 0u;
    lds[tid] = bv;
    __syncthreads();
    for (int off = 128; off > 0; off >>= 1) {
        if (tid < off) lds[tid] += lds[tid + off];
        __syncthreads();
    }
    if (tid == 0) block_base = lds[0];
    __syncthreads();

    int base = blockIdx.x * 1024 + tid * 4;
    unsigned d0 = 0, d1 = 0, d2 = 0, d3 = 0;
    bool full = (base + 3 < n);
    if (full) {
        uint4 v = *(const uint4*)(deg + base);
        d0 = v.x; d1 = v.y; d2 = v.z; d3 = v.w;
    } else {
        if (base + 0 < n) d0 = deg[base + 0];
        if (base + 1 < n) d1 = deg[base + 1];
        if (base + 2 < n) d2 = deg[base + 2];
    }
    unsigned s = d0 + d1 + d2 + d3;
    __syncthreads();   // lds about to be reused
    lds[tid] = s;
    __syncthreads();
    for (int off = 1; off < 256; off <<= 1) {
        unsigned t = (tid >= off) ? lds[tid - off] : 0u;
        __syncthreads();
        lds[tid] += t;
        __syncthreads();
    }
    unsigned run = block_base + lds[tid] - s;  // exclusive prefix at base
    unsigned r0 = run, r1 = r0 + d0, r2 = r1 + d1, r3 = r2 + d2;
    if (full) {
        *(uint4*)(row_start + base) = make_uint4(r0, r1, r2, r3);
        *(float4*)(dinv + base) = make_float4(rsqrtf((float)(d0 + 1u)), rsqrtf((float)(d1 + 1u)),
                                              rsqrtf((float)(d2 + 1u)), rsqrtf((float)(d3 + 1u)));
    } else {
        unsigned r[4] = {r0, r1, r2, r3};
        unsigned d[4] = {d0, d1, d2, d3};
        for (int i = 0; i < 4; ++i)
            if (base + i < n) {
                row_start[base + i] = r[i];
                dinv[base + i] = rsqrtf((float)(d[i] + 1u));
            }
    }
}

// No atomics: absolute slot = row_start[dst] + rank.  8 edges per iteration.
__global__ void k_fillr(const int* __restrict__ src, const int* __restrict__ dst,
                        const unsigned* __restrict__ rank, int E,
                        const unsigned* __restrict__ row_start,
                        unsigned* __restrict__ csr_src) {
    int gid = blockIdx.x * blockDim.x + threadIdx.x;
    int stride = gridDim.x * blockDim.x;
    int nquad = E >> 2;
    int npair = nquad >> 1;
    for (int p = gid; p < npair; p += stride) {
        int4 sa = *(const int4*)(src + (size_t)p * 4);
        int4 da = *(const int4*)(dst + (size_t)p * 4);
        uint4 ra = *(const uint4*)(rank + (size_t)p * 4);
        int4 sb = *(const int4*)(src + (size_t)(npair + p) * 4);
        int4 db = *(const int4*)(dst + (size_t)(npair + p) * 4);
        uint4 rb = *(const uint4*)(rank + (size_t)(npair + p) * 4);
        unsigned q0 = row_start[da.x];
        unsigned q1 = row_start[da.y];
        unsigned q2 = row_start[da.z];
        unsigned q3 = row_start[da.w];
        unsigned q4 = row_start[db.x];
        unsigned q5 = row_start[db.y];
        unsigned q6 = row_start[db.z];
        unsigned q7 = row_start[db.w];
        csr_src[q0 + ra.x] = (unsigned)sa.x;
        csr_src[q1 + ra.y] = (unsigned)sa.y;
        csr_src[q2 + ra.z] = (unsigned)sa.z;
        csr_src[q3 + ra.w] = (unsigned)sa.w;
        csr_src[q4 + rb.x] = (unsigned)sb.x;
        csr_src[q5 + rb.y] = (unsigned)sb.y;
        csr_src[q6 + rb.z] = (unsigned)sb.z;
        csr_src[q7 + rb.w] = (unsigned)sb.w;
    }
    for (int t = npair * 8 + gid; t < E; t += stride)
        csr_src[row_start[dst[t]] + rank[t]] = (unsigned)src[t];
}

// g1[v] = bf16( (x[v] @ W1) * dinv[v] )  -- persistent, 64-node tiles, 4x4 reg block
__global__ __launch_bounds__(256) void k_gemm1(const float* __restrict__ x,
                                               const float* __restrict__ W1,
                                               const float* __restrict__ dinv, int n,
                                               __hip_bfloat16* __restrict__ g1) {
    __shared__ __align__(16) float w1s[64 * 64];   // [k][c], 16KB
    __shared__ __align__(16) float xs[64 * 68];    // [k][node], pad 68, 17.4KB
    int tid = threadIdx.x;
    int w = tid >> 6, lane = tid & 63;
    int cg = lane & 15, ng = lane >> 4;   // channels cg*4..+3, nodes w*16+ng*4..+3

    for (int r = 0; r < 4; ++r) {
        int idx = r * 256 + tid;
        *(float4*)&w1s[idx * 4] = *(const float4*)&W1[idx * 4];
    }

    int ntiles = (n + 63) >> 6;
    for (int tile = blockIdx.x; tile < ntiles; tile += gridDim.x) {
        int v0 = tile << 6;
        __syncthreads();   // protect xs from previous iteration's readers
        for (int r = 0; r < 4; ++r) {
            int flat = r * 1024 + tid * 4;
            int node = flat >> 6, k0 = flat & 63;
            int v = v0 + node;
            float4 xv = (v < n) ? *(const float4*)&x[(size_t)v * 64 + k0]
                                : make_float4(0.f, 0.f, 0.f, 0.f);
            xs[(k0 + 0) * 68 + node] = xv.x;
            xs[(k0 + 1) * 68 + node] = xv.y;
            xs[(k0 + 2) * 68 + node] = xv.z;
            xs[(k0 + 3) * 68 + node] = xv.w;
        }
        __syncthreads();

        float4 acc[4] = {{0,0,0,0},{0,0,0,0},{0,0,0,0},{0,0,0,0}};
        int nbase = w * 16 + ng * 4;
#pragma unroll
        for (int k = 0; k < 64; ++k) {
            float4 xv = *(float4*)&xs[k * 68 + nbase];
            float4 wv = *(float4*)&w1s[k * 64 + cg * 4];
            acc[0].x += xv.x * wv.x; acc[0].y += xv.x * wv.y;
            acc[0].z += xv.x * wv.z; acc[0].w += xv.x * wv.w;
            acc[1].x += xv.y * wv.x; acc[1].y += xv.y * wv.y;
            acc[1].z += xv.y * wv.z; acc[1].w += xv.y * wv.w;
            acc[2].x += xv.z * wv.x; acc[2].y += xv.z * wv.y;
            acc[2].z += xv.z * wv.z; acc[2].w += xv.z * wv.w;
            acc[3].x += xv.w * wv.x; acc[3].y += xv.w * wv.y;
            acc[3].z += xv.w * wv.z; acc[3].w += xv.w * wv.w;
        }
        for (int a = 0; a < 4; ++a) {
            int v = v0 + nbase + a;
            if (v < n) {
                float dv = dinv[v];
                bfpack4 pk;
                pk.h[0] = __float2bfloat16(acc[a].x * dv);
                pk.h[1] = __float2bfloat16(acc[a].y * dv);
                pk.h[2] = __float2bfloat16(acc[a].z * dv);
                pk.h[3] = __float2bfloat16(acc[a].w * dv);
                *(ushort4*)&g1[(size_t)v * 64 + cg * 4] = pk.u;
            }
        }
    }
}

// h1p[v] = dinv[v]*(g1[v] + sum_{u->v} g1[u]) + b1 ; BN partial sums (f64).
__global__ __launch_bounds__(256) void k_agg1(const __hip_bfloat16* __restrict__ g1,
                                              const unsigned* __restrict__ row_start,
                                              const unsigned* __restrict__ deg,
                                              const unsigned* __restrict__ csr_src,
                                              const float* __restrict__ dinv,
                                              const float* __restrict__ b1, int n,
                                              float* __restrict__ h1p,
                                              double* __restrict__ bn_part) {
    int tid = threadIdx.x;
    int lane = tid & 63, w = tid >> 6;
    int waveId = blockIdx.x * 4 + w;
    int nWaves = gridDim.x * 4;
    double lsum = 0.0, lsq = 0.0;
    float bb = b1[lane];
    for (int v = waveId; v < n; v += nWaves) {
        float dv = dinv[v];
        unsigned start = row_start[v], cnt = deg[v];
        float acc = __bfloat162float(g1[(size_t)v * 64 + lane]);   // self-loop
        unsigned j = 0;
        for (; j + 8 <= cnt; j += 8) {   // 8 independent 128B gathers in flight
            unsigned u0 = csr_src[start + j + 0];
            unsigned u1 = csr_src[start + j + 1];
            unsigned u2 = csr_src[start + j + 2];
            unsigned u3 = csr_src[start + j + 3];
            unsigned u4 = csr_src[start + j + 4];
            unsigned u5 = csr_src[start + j + 5];
            unsigned u6 = csr_src[start + j + 6];
            unsigned u7 = csr_src[start + j + 7];
            float f0 = __bfloat162float(g1[(size_t)u0 * 64 + lane]);
            float f1 = __bfloat162float(g1[(size_t)u1 * 64 + lane]);
            float f2 = __bfloat162float(g1[(size_t)u2 * 64 + lane]);
            float f3 = __bfloat162float(g1[(size_t)u3 * 64 + lane]);
            float f4 = __bfloat162float(g1[(size_t)u4 * 64 + lane]);
            float f5 = __bfloat162float(g1[(size_t)u5 * 64 + lane]);
            float f6 = __bfloat162float(g1[(size_t)u6 * 64 + lane]);
            float f7 = __bfloat162float(g1[(size_t)u7 * 64 + lane]);
            acc += ((f0 + f1) + (f2 + f3)) + ((f4 + f5) + (f6 + f7));
        }
        for (; j + 4 <= cnt; j += 4) {
            unsigned u0 = csr_src[start + j + 0];
            unsigned u1 = csr_src[start + j + 1];
            unsigned u2 = csr_src[start + j + 2];
            unsigned u3 = csr_src[start + j + 3];
            float f0 = __bfloat162float(g1[(size_t)u0 * 64 + lane]);
            float f1 = __bfloat162float(g1[(size_t)u1 * 64 + lane]);
            float f2 = __bfloat162float(g1[(size_t)u2 * 64 + lane]);
            float f3 = __bfloat162float(g1[(size_t)u3 * 64 + lane]);
            acc += (f0 + f1) + (f2 + f3);
        }
        for (; j < cnt; ++j) {
            unsigned u = csr_src[start + j];
            acc += __bfloat162float(g1[(size_t)u * 64 + lane]);
        }
        float val = dv * acc + bb;
        h1p[(size_t)v * 64 + lane] = val;
        lsum += (double)val;
        lsq  += (double)val * (double)val;
    }
    __shared__ double red[4][64][2];
    red[w][lane][0] = lsum;
    red[w][lane][1] = lsq;
    __syncthreads();
    if (tid < 64) {
        double s = red[0][tid][0] + red[1][tid][0] + red[2][tid][0] + red[3][tid][0];
        double q = red[0][tid][1] + red[1][tid][1] + red[2][tid][1] + red[3][tid][1];
        double* p = bn_part + (size_t)(blockIdx.x & 7) * 128;  // 8-way sharded
        atomicAdd(&p[tid], s);
        atomicAdd(&p[64 + tid], q);
    }
}

// BN params recomputed per block (saves a launch); y = relu(h1p*sc+sh);
// g2[v] = bf16( (y[v]@W2) * dinv[v] ) -- persistent, 64-node tiles
__global__ __launch_bounds__(256) void k_bn_gemm2(const float* __restrict__ h1p,
                                                  const float* __restrict__ W2,
                                                  const double* __restrict__ bn_part,
                                                  const float* __restrict__ gamma,
                                                  const float* __restrict__ beta,
                                                  const float* __restrict__ dinv, int n,
                                                  __hip_bfloat16* __restrict__ g2) {
    __shared__ __align__(16) float w2s[64 * 16];   // [k][c], 4KB
    __shared__ __align__(16) float ys[64 * 68];    // [k][node], 17.4KB
    __shared__ float bnsc[64], bnsh[64];
    int tid = threadIdx.x;
    int w = tid >> 6, lane = tid & 63;
    int cg = lane & 3, ng = lane >> 2;   // channels cg*4..+3, node w*16+ng

    *(float4*)&w2s[tid * 4] = *(const float4*)&W2[tid * 4];   // 256*4 = 1024 exactly
    if (tid < 64) {
        double s = 0.0, q = 0.0;
        for (int p = 0; p < 8; ++p) {
            s += bn_part[p * 128 + tid];
            q += bn_part[p * 128 + 64 + tid];
        }
        double mean = s / n;
        double var = q / n - mean * mean;
        if (var < 0.0) var = 0.0;
        float scale = gamma[tid] * (float)(1.0 / sqrt(var + 1e-5));
        bnsc[tid] = scale;
        bnsh[tid] = beta[tid] - (float)mean * scale;
    }

    int ntiles = (n + 63) >> 6;
    for (int tile = blockIdx.x; tile < ntiles; tile += gridDim.x) {
        int v0 = tile << 6;
        __syncthreads();
        for (int r = 0; r < 4; ++r) {
            int flat = r * 1024 + tid * 4;
            int node = flat >> 6, k0 = flat & 63;
            int v = v0 + node;
            float4 hv = (v < n) ? *(const float4*)&h1p[(size_t)v * 64 + k0]
                                : make_float4(0.f, 0.f, 0.f, 0.f);
            ys[(k0 + 0) * 68 + node] = fmaxf(hv.x * bnsc[k0 + 0] + bnsh[k0 + 0], 0.f);
            ys[(k0 + 1) * 68 + node] = fmaxf(hv.y * bnsc[k0 + 1] + bnsh[k0 + 1], 0.f);
            ys[(k0 + 2) * 68 + node] = fmaxf(hv.z * bnsc[k0 + 2] + bnsh[k0 + 2], 0.f);
            ys[(k0 + 3) * 68 + node] = fmaxf(hv.w * bnsc[k0 + 3] + bnsh[k0 + 3], 0.f);
        }
        __syncthreads();

        float4 acc = {0, 0, 0, 0};
        int node = w * 16 + ng;
#pragma unroll
        for (int k = 0; k < 64; ++k) {
            float xv = ys[k * 68 + node];
            float4 wv = *(float4*)&w2s[k * 16 + cg * 4];
            acc.x += xv * wv.x; acc.y += xv * wv.y;
            acc.z += xv * wv.z; acc.w += xv * wv.w;
        }
        int v = v0 + node;
        if (v < n) {
            float dv = dinv[v];
            bfpack4 pk;
            pk.h[0] = __float2bfloat16(acc.x * dv);
            pk.h[1] = __float2bfloat16(acc.y * dv);
            pk.h[2] = __float2bfloat16(acc.z * dv);
            pk.h[3] = __float2bfloat16(acc.w * dv);
            *(ushort4*)&g2[(size_t)v * 16 + cg * 4] = pk.u;
        }
    }
}

// out[v] = dinv[v]*(g2[v] + sum_{u->v} g2[u]) + b2   (C=16; 16-lane groups)
__global__ __launch_bounds__(256) void k_agg2(const __hip_bfloat16* __restrict__ g2,
                                              const unsigned* __restrict__ row_start,
                                              const unsigned* __restrict__ deg,
                                              const unsigned* __restrict__ csr_src,
                                              const float* __restrict__ dinv,
                                              const float* __restrict__ b2, int n,
                                              float* __restrict__ out) {
    int tid = threadIdx.x;
    int lane = tid & 63, w = tid >> 6;
    int c = lane & 15, jg = lane >> 4;
    int waveId = blockIdx.x * 4 + w;
    int nWaves = gridDim.x * 4;
    for (int v = waveId; v < n; v += nWaves) {
        unsigned start = row_start[v], cnt = deg[v];
        float acc = (jg == 0) ? __bfloat162float(g2[(size_t)v * 16 + c]) : 0.f;
        unsigned j = jg;
        for (; j + 16 <= cnt; j += 16) {   // 4 lines in flight per group
            unsigned u0 = csr_src[start + j];
            unsigned u1 = csr_src[start + j + 4];
            unsigned u2 = csr_src[start + j + 8];
            unsigned u3 = csr_src[start + j + 12];
            float f0 = __bfloat162float(g2[(size_t)u0 * 16 + c]);
            float f1 = __bfloat162float(g2[(size_t)u1 * 16 + c]);
            float f2 = __bfloat162float(g2[(size_t)u2 * 16 + c]);
            float f3 = __bfloat162float(g2[(size_t)u3 * 16 + c]);
            acc += (f0 + f1) + (f2 + f3);
        }
        for (; j + 8 <= cnt; j += 8) {
            unsigned u0 = csr_src[start + j];
            unsigned u1 = csr_src[start + j + 4];
            float f0 = __bfloat162float(g2[(size_t)u0 * 16 + c]);
            float f1 = __bfloat162float(g2[(size_t)u1 * 16 + c]);
            acc += f0 + f1;
        }
        for (; j < cnt; j += 4) {
            unsigned u = csr_src[start + j];
            acc += __bfloat162float(g2[(size_t)u * 16 + c]);
        }
        acc += __shfl_xor(acc, 16, 64);
        acc += __shfl_xor(acc, 32, 64);
        if (jg == 0) out[(size_t)v * 16 + c] = dinv[v] * acc + b2[c];
    }
}

extern "C" void kernel_launch(void* const* d_in, const int* in_sizes, int n_in,
                              void* d_out, int out_size, void* d_ws, size_t ws_size,
                              hipStream_t stream) {
    const float* x     = (const float*)d_in[0];
    const int*   ei    = (const int*)d_in[1];
    const float* W1    = (const float*)d_in[2];
    const float* b1    = (const float*)d_in[3];
    const float* gamma = (const float*)d_in[4];
    const float* beta  = (const float*)d_in[5];
    const float* W2    = (const float*)d_in[6];
    const float* b2    = (const float*)d_in[7];
    float* out = (float*)d_out;

    int n = in_sizes[0] / 64;
    int E = in_sizes[1] / 2;
    const int* esrc = ei;
    const int* edst = ei + E;

    char* ws = (char*)d_ws;
    size_t off = 0;
    auto alloc = [&](size_t bytes) {
        size_t o = off;
        off += (bytes + 255) & ~(size_t)255;
        return o;
    };
    unsigned* deg       = (unsigned*)(ws + alloc((size_t)n * 4));
    unsigned* row_start = (unsigned*)(ws + alloc((size_t)n * 4));
    float*    dinv      = (float*)(ws + alloc((size_t)n * 4));
    unsigned* csr_src   = (unsigned*)(ws + alloc((size_t)E * 4));
    __hip_bfloat16* g1  = (__hip_bfloat16*)(ws + alloc((size_t)n * 64 * 2));
    // union region: rank (E*4, dead after k_fillr) aliases h1p (n*64*4, born in k_agg1)
    size_t uoff = alloc((((size_t)E * 4) > ((size_t)n * 64 * 4)) ? (size_t)E * 4
                                                                 : (size_t)n * 64 * 4);
    unsigned* rank      = (unsigned*)(ws + uoff);
    float*    h1p       = (float*)(ws + uoff);
    __hip_bfloat16* g2  = (__hip_bfloat16*)(ws + alloc((size_t)n * 16 * 2));
    double*   bn_part   = (double*)(ws + alloc(8 * 128 * 8));
    unsigned* bsum      = (unsigned*)(ws + alloc(1024 * 4));

    hipMemsetAsync(deg, 0, (size_t)n * 4, stream);
    hipMemsetAsync(bn_part, 0, 8 * 128 * 8, stream);

    int nbs = (n + 1023) / 1024;   // 98 for n=100000 (must be <= 256)
    int npair = (E >> 2) >> 1;
    int drBlocks = (npair + 255) / 256;   // 782: one 8-edge pack per thread

    k_degrank<<<drBlocks, 256, 0, stream>>>(edst, E, deg, rank);
    k_bsum<<<nbs, 256, 0, stream>>>(deg, n, bsum);
    k_scanwrite<<<nbs, 256, 0, stream>>>(deg, bsum, nbs, n, row_start, dinv);
    k_fillr<<<1024, 256, 0, stream>>>(esrc, edst, rank, E, row_start, csr_src);
    k_gemm1<<<512, 256, 0, stream>>>(x, W1, dinv, n, g1);
    k_agg1<<<2048, 256, 0, stream>>>(g1, row_start, deg, csr_src, dinv, b1, n, h1p, bn_part);
    k_bn_gemm2<<<512, 256, 0, stream>>>(h1p, W2, bn_part, gamma, beta, dinv, n, g2);
    k_agg2<<<2048, 256, 0, stream>>>(g2, row_start, deg, csr_src, dinv, b2, n, out);
}

// Round 15
// 278.664 us; speedup vs baseline: 1.2109x; 1.1919x over previous
//
#include <hip/hip_runtime.h>
#include <hip/hip_bf16.h>

// GCN 2-layer: N=100000 nodes, E=1600000 edges, F=64, H=64, C=16.
// GCNConv: out[v] = dinv[v]*( g[v] + sum_{u->v} g[u] ) + b,  g[u] = (x[u]@W)*dinv[u]
// g1/g2 stored bf16; accumulation f32.
// MEASURED WALLS: per-edge device-scope atomic RMW ~23G/s (degrank 69us flat,
// R7/R8/R12); fully-random 4B scatter ~55us (fillr, sector write-amp);
// fused divergent kernels: branch-max VGPR / spill hazards (R10/R11/R13).
// Round 15: bucketed CSR build -- NO per-edge global atomics.
//   k_hist:  per-block LDS hist over NB=196 buckets (dst>>9), reserve ranges
//            via 512x196 = 100K global atomics (16x fewer than degrank).
//   k_bstart: 196-entry scan -> bucket_start.
//   k_part:  scatter packed (src | dstlow<<17) via LDS cursors into reserved
//            runs (sequential per (block,bucket) -> L2 merges write sectors).
//   k_bcsr:  per-bucket (512 nodes) LDS deg hist + scan; writes deg/row_start/
//            dinv coalesced and csr_src within a 32KB L2-resident window.
// part[] aliases h1p[] (dead before k_agg1).  Edge order within a row is
// permuted vs input -- legal (row aggregation is a sum).

#define PB 512          // partition blocks; k_hist and k_part MUST share ranges
#define NB_SHIFT 9      // 512 nodes per bucket; nb = ceil(n/512) <= 256 required

union bfpack4 { ushort4 u; __hip_bfloat16 h[4]; };

__global__ __launch_bounds__(256) void k_hist(const int* __restrict__ dst, int E, int nb,
                                              unsigned* __restrict__ cursor_within,
                                              unsigned* __restrict__ resv) {
    __shared__ unsigned histL[256];
    int tid = threadIdx.x;
    for (int b = tid; b < nb; b += 256) histL[b] = 0u;
    __syncthreads();
    size_t lo = (size_t)blockIdx.x * E / PB;
    size_t hi = (size_t)(blockIdx.x + 1) * E / PB;
    for (size_t e = lo + tid; e < hi; e += 256)
        atomicAdd(&histL[((unsigned)dst[e]) >> NB_SHIFT], 1u);
    __syncthreads();
    for (int b = tid; b < nb; b += 256)
        resv[(size_t)blockIdx.x * nb + b] = atomicAdd(&cursor_within[b], histL[b]);
}

__global__ void k_bstart(const unsigned* __restrict__ total, int nb,
                         unsigned* __restrict__ bucket_start) {
    __shared__ unsigned lds[256];
    int tid = threadIdx.x;
    unsigned v = (tid < nb) ? total[tid] : 0u;
    lds[tid] = v;
    __syncthreads();
    for (int off = 1; off < 256; off <<= 1) {
        unsigned t = (tid >= off) ? lds[tid - off] : 0u;
        __syncthreads();
        lds[tid] += t;
        __syncthreads();
    }
    if (tid < nb) bucket_start[tid] = lds[tid] - v;  // exclusive
}

__global__ __launch_bounds__(256) void k_part(const int* __restrict__ src,
                                              const int* __restrict__ dst, int E, int nb,
                                              const unsigned* __restrict__ resv,
                                              const unsigned* __restrict__ bucket_start,
                                              unsigned* __restrict__ part) {
    __shared__ unsigned curL[256];
    int tid = threadIdx.x;
    for (int b = tid; b < nb; b += 256)
        curL[b] = bucket_start[b] + resv[(size_t)blockIdx.x * nb + b];
    __syncthreads();
    size_t lo = (size_t)blockIdx.x * E / PB;
    size_t hi = (size_t)(blockIdx.x + 1) * E / PB;
    for (size_t e = lo + tid; e < hi; e += 256) {
        unsigned d = (unsigned)dst[e];
        unsigned s = (unsigned)src[e];
        unsigned slot = atomicAdd(&curL[d >> NB_SHIFT], 1u);   // LDS atomic
        part[slot] = s | ((d & ((1u << NB_SHIFT) - 1u)) << 17);  // src<2^17
    }
}

__global__ __launch_bounds__(256) void k_bcsr(const unsigned* __restrict__ part,
                                              const unsigned* __restrict__ bucket_start,
                                              const unsigned* __restrict__ total,
                                              int n,
                                              unsigned* __restrict__ deg,
                                              unsigned* __restrict__ row_start,
                                              float* __restrict__ dinv,
                                              unsigned* __restrict__ csr_src) {
    __shared__ unsigned degL[512];
    __shared__ unsigned curL[512];
    __shared__ unsigned scanT[256];
    int tid = threadIdx.x;
    int b = blockIdx.x;
    unsigned e0 = bucket_start[b], cnt = total[b];
    degL[tid] = 0u;
    degL[tid + 256] = 0u;
    __syncthreads();
    for (unsigned i = tid; i < cnt; i += 256)
        atomicAdd(&degL[part[e0 + i] >> 17], 1u);
    __syncthreads();
    // exclusive scan of 512 entries (2 per thread)
    unsigned a = degL[2 * tid], b2 = degL[2 * tid + 1];
    unsigned s = a + b2;
    scanT[tid] = s;
    __syncthreads();
    for (int off = 1; off < 256; off <<= 1) {
        unsigned t = (tid >= off) ? scanT[tid - off] : 0u;
        __syncthreads();
        scanT[tid] += t;
        __syncthreads();
    }
    unsigned excl = scanT[tid] - s;
    curL[2 * tid] = excl;
    curL[2 * tid + 1] = excl + a;
    __syncthreads();
    // node outputs (coalesced)
    int vbase = b << NB_SHIFT;
    for (int i = tid; i < 512; i += 256) {
        int v = vbase + i;
        if (v < n) {
            unsigned dgi = degL[i];
            deg[v] = dgi;
            row_start[v] = e0 + curL[i];
            dinv[v] = rsqrtf((float)(dgi + 1u));
        }
    }
    __syncthreads();
    // scatter within the bucket's 32KB window
    for (unsigned i = tid; i < cnt; i += 256) {
        unsigned p = part[e0 + i];
        unsigned slot = atomicAdd(&curL[p >> 17], 1u);   // LDS atomic
        csr_src[e0 + slot] = p & 0x1FFFFu;
    }
}

// g1[v] = bf16( (x[v] @ W1) * dinv[v] )  -- persistent, 64-node tiles, 4x4 reg block
__global__ __launch_bounds__(256) void k_gemm1(const float* __restrict__ x,
                                               const float* __restrict__ W1,
                                               const float* __restrict__ dinv, int n,
                                               __hip_bfloat16* __restrict__ g1) {
    __shared__ __align__(16) float w1s[64 * 64];   // [k][c], 16KB
    __shared__ __align__(16) float xs[64 * 68];    // [k][node], pad 68, 17.4KB
    int tid = threadIdx.x;
    int w = tid >> 6, lane = tid & 63;
    int cg = lane & 15, ng = lane >> 4;   // channels cg*4..+3, nodes w*16+ng*4..+3

    for (int r = 0; r < 4; ++r) {
        int idx = r * 256 + tid;
        *(float4*)&w1s[idx * 4] = *(const float4*)&W1[idx * 4];
    }

    int ntiles = (n + 63) >> 6;
    for (int tile = blockIdx.x; tile < ntiles; tile += gridDim.x) {
        int v0 = tile << 6;
        __syncthreads();   // protect xs from previous iteration's readers
        for (int r = 0; r < 4; ++r) {
            int flat = r * 1024 + tid * 4;
            int node = flat >> 6, k0 = flat & 63;
            int v = v0 + node;
            float4 xv = (v < n) ? *(const float4*)&x[(size_t)v * 64 + k0]
                                : make_float4(0.f, 0.f, 0.f, 0.f);
            xs[(k0 + 0) * 68 + node] = xv.x;
            xs[(k0 + 1) * 68 + node] = xv.y;
            xs[(k0 + 2) * 68 + node] = xv.z;
            xs[(k0 + 3) * 68 + node] = xv.w;
        }
        __syncthreads();

        float4 acc[4] = {{0,0,0,0},{0,0,0,0},{0,0,0,0},{0,0,0,0}};
        int nbase = w * 16 + ng * 4;
#pragma unroll
        for (int k = 0; k < 64; ++k) {
            float4 xv = *(float4*)&xs[k * 68 + nbase];
            float4 wv = *(float4*)&w1s[k * 64 + cg * 4];
            acc[0].x += xv.x * wv.x; acc[0].y += xv.x * wv.y;
            acc[0].z += xv.x * wv.z; acc[0].w += xv.x * wv.w;
            acc[1].x += xv.y * wv.x; acc[1].y += xv.y * wv.y;
            acc[1].z += xv.y * wv.z; acc[1].w += xv.y * wv.w;
            acc[2].x += xv.z * wv.x; acc[2].y += xv.z * wv.y;
            acc[2].z += xv.z * wv.z; acc[2].w += xv.z * wv.w;
            acc[3].x += xv.w * wv.x; acc[3].y += xv.w * wv.y;
            acc[3].z += xv.w * wv.z; acc[3].w += xv.w * wv.w;
        }
        for (int a = 0; a < 4; ++a) {
            int v = v0 + nbase + a;
            if (v < n) {
                float dv = dinv[v];
                bfpack4 pk;
                pk.h[0] = __float2bfloat16(acc[a].x * dv);
                pk.h[1] = __float2bfloat16(acc[a].y * dv);
                pk.h[2] = __float2bfloat16(acc[a].z * dv);
                pk.h[3] = __float2bfloat16(acc[a].w * dv);
                *(ushort4*)&g1[(size_t)v * 64 + cg * 4] = pk.u;
            }
        }
    }
}

// h1p[v] = dinv[v]*(g1[v] + sum_{u->v} g1[u]) + b1 ; BN partial sums (f64).
__global__ __launch_bounds__(256) void k_agg1(const __hip_bfloat16* __restrict__ g1,
                                              const unsigned* __restrict__ row_start,
                                              const unsigned* __restrict__ deg,
                                              const unsigned* __restrict__ csr_src,
                                              const float* __restrict__ dinv,
                                              const float* __restrict__ b1, int n,
                                              float* __restrict__ h1p,
                                              double* __restrict__ bn_part) {
    int tid = threadIdx.x;
    int lane = tid & 63, w = tid >> 6;
    int waveId = blockIdx.x * 4 + w;
    int nWaves = gridDim.x * 4;
    double lsum = 0.0, lsq = 0.0;
    float bb = b1[lane];
    for (int v = waveId; v < n; v += nWaves) {
        float dv = dinv[v];
        unsigned start = row_start[v], cnt = deg[v];
        float acc = __bfloat162float(g1[(size_t)v * 64 + lane]);   // self-loop
        unsigned j = 0;
        for (; j + 8 <= cnt; j += 8) {   // 8 independent 128B gathers in flight
            unsigned u0 = csr_src[start + j + 0];
            unsigned u1 = csr_src[start + j + 1];
            unsigned u2 = csr_src[start + j + 2];
            unsigned u3 = csr_src[start + j + 3];
            unsigned u4 = csr_src[start + j + 4];
            unsigned u5 = csr_src[start + j + 5];
            unsigned u6 = csr_src[start + j + 6];
            unsigned u7 = csr_src[start + j + 7];
            float f0 = __bfloat162float(g1[(size_t)u0 * 64 + lane]);
            float f1 = __bfloat162float(g1[(size_t)u1 * 64 + lane]);
            float f2 = __bfloat162float(g1[(size_t)u2 * 64 + lane]);
            float f3 = __bfloat162float(g1[(size_t)u3 * 64 + lane]);
            float f4 = __bfloat162float(g1[(size_t)u4 * 64 + lane]);
            float f5 = __bfloat162float(g1[(size_t)u5 * 64 + lane]);
            float f6 = __bfloat162float(g1[(size_t)u6 * 64 + lane]);
            float f7 = __bfloat162float(g1[(size_t)u7 * 64 + lane]);
            acc += ((f0 + f1) + (f2 + f3)) + ((f4 + f5) + (f6 + f7));
        }
        for (; j + 4 <= cnt; j += 4) {
            unsigned u0 = csr_src[start + j + 0];
            unsigned u1 = csr_src[start + j + 1];
            unsigned u2 = csr_src[start + j + 2];
            unsigned u3 = csr_src[start + j + 3];
            float f0 = __bfloat162float(g1[(size_t)u0 * 64 + lane]);
            float f1 = __bfloat162float(g1[(size_t)u1 * 64 + lane]);
            float f2 = __bfloat162float(g1[(size_t)u2 * 64 + lane]);
            float f3 = __bfloat162float(g1[(size_t)u3 * 64 + lane]);
            acc += (f0 + f1) + (f2 + f3);
        }
        for (; j < cnt; ++j) {
            unsigned u = csr_src[start + j];
            acc += __bfloat162float(g1[(size_t)u * 64 + lane]);
        }
        float val = dv * acc + bb;
        h1p[(size_t)v * 64 + lane] = val;
        lsum += (double)val;
        lsq  += (double)val * (double)val;
    }
    __shared__ double red[4][64][2];
    red[w][lane][0] = lsum;
    red[w][lane][1] = lsq;
    __syncthreads();
    if (tid < 64) {
        double s = red[0][tid][0] + red[1][tid][0] + red[2][tid][0] + red[3][tid][0];
        double q = red[0][tid][1] + red[1][tid][1] + red[2][tid][1] + red[3][tid][1];
        double* p = bn_part + (size_t)(blockIdx.x & 7) * 128;  // 8-way sharded
        atomicAdd(&p[tid], s);
        atomicAdd(&p[64 + tid], q);
    }
}

// BN params recomputed per block; y = relu(h1p*sc+sh);
// g2[v] = bf16( (y[v]@W2) * dinv[v] ) -- persistent, 64-node tiles
__global__ __launch_bounds__(256) void k_bn_gemm2(const float* __restrict__ h1p,
                                                  const float* __restrict__ W2,
                                                  const double* __restrict__ bn_part,
                                                  const float* __restrict__ gamma,
                                                  const float* __restrict__ beta,
                                                  const float* __restrict__ dinv, int n,
                                                  __hip_bfloat16* __restrict__ g2) {
    __shared__ __align__(16) float w2s[64 * 16];   // [k][c], 4KB
    __shared__ __align__(16) float ys[64 * 68];    // [k][node], 17.4KB
    __shared__ float bnsc[64], bnsh[64];
    int tid = threadIdx.x;
    int w = tid >> 6, lane = tid & 63;
    int cg = lane & 3, ng = lane >> 2;   // channels cg*4..+3, node w*16+ng

    *(float4*)&w2s[tid * 4] = *(const float4*)&W2[tid * 4];   // 256*4 = 1024 exactly
    if (tid < 64) {
        double s = 0.0, q = 0.0;
        for (int p = 0; p < 8; ++p) {
            s += bn_part[p * 128 + tid];
            q += bn_part[p * 128 + 64 + tid];
        }
        double mean = s / n;
        double var = q / n - mean * mean;
        if (var < 0.0) var = 0.0;
        float scale = gamma[tid] * (float)(1.0 / sqrt(var + 1e-5));
        bnsc[tid] = scale;
        bnsh[tid] = beta[tid] - (float)mean * scale;
    }

    int ntiles = (n + 63) >> 6;
    for (int tile = blockIdx.x; tile < ntiles; tile += gridDim.x) {
        int v0 = tile << 6;
        __syncthreads();
        for (int r = 0; r < 4; ++r) {
            int flat = r * 1024 + tid * 4;
            int node = flat >> 6, k0 = flat & 63;
            int v = v0 + node;
            float4 hv = (v < n) ? *(const float4*)&h1p[(size_t)v * 64 + k0]
                                : make_float4(0.f, 0.f, 0.f, 0.f);
            ys[(k0 + 0) * 68 + node] = fmaxf(hv.x * bnsc[k0 + 0] + bnsh[k0 + 0], 0.f);
            ys[(k0 + 1) * 68 + node] = fmaxf(hv.y * bnsc[k0 + 1] + bnsh[k0 + 1], 0.f);
            ys[(k0 + 2) * 68 + node] = fmaxf(hv.z * bnsc[k0 + 2] + bnsh[k0 + 2], 0.f);
            ys[(k0 + 3) * 68 + node] = fmaxf(hv.w * bnsc[k0 + 3] + bnsh[k0 + 3], 0.f);
        }
        __syncthreads();

        float4 acc = {0, 0, 0, 0};
        int node = w * 16 + ng;
#pragma unroll
        for (int k = 0; k < 64; ++k) {
            float xv = ys[k * 68 + node];
            float4 wv = *(float4*)&w2s[k * 16 + cg * 4];
            acc.x += xv * wv.x; acc.y += xv * wv.y;
            acc.z += xv * wv.z; acc.w += xv * wv.w;
        }
        int v = v0 + node;
        if (v < n) {
            float dv = dinv[v];
            bfpack4 pk;
            pk.h[0] = __float2bfloat16(acc.x * dv);
            pk.h[1] = __float2bfloat16(acc.y * dv);
            pk.h[2] = __float2bfloat16(acc.z * dv);
            pk.h[3] = __float2bfloat16(acc.w * dv);
            *(ushort4*)&g2[(size_t)v * 16 + cg * 4] = pk.u;
        }
    }
}

// out[v] = dinv[v]*(g2[v] + sum_{u->v} g2[u]) + b2   (C=16; 16-lane groups)
__global__ __launch_bounds__(256) void k_agg2(const __hip_bfloat16* __restrict__ g2,
                                              const unsigned* __restrict__ row_start,
                                              const unsigned* __restrict__ deg,
                                              const unsigned* __restrict__ csr_src,
                                              const float* __restrict__ dinv,
                                              const float* __restrict__ b2, int n,
                                              float* __restrict__ out) {
    int tid = threadIdx.x;
    int lane = tid & 63, w = tid >> 6;
    int c = lane & 15, jg = lane >> 4;
    int waveId = blockIdx.x * 4 + w;
    int nWaves = gridDim.x * 4;
    for (int v = waveId; v < n; v += nWaves) {
        unsigned start = row_start[v], cnt = deg[v];
        float acc = (jg == 0) ? __bfloat162float(g2[(size_t)v * 16 + c]) : 0.f;
        unsigned j = jg;
        for (; j + 16 <= cnt; j += 16) {   // 4 lines in flight per group
            unsigned u0 = csr_src[start + j];
            unsigned u1 = csr_src[start + j + 4];
            unsigned u2 = csr_src[start + j + 8];
            unsigned u3 = csr_src[start + j + 12];
            float f0 = __bfloat162float(g2[(size_t)u0 * 16 + c]);
            float f1 = __bfloat162float(g2[(size_t)u1 * 16 + c]);
            float f2 = __bfloat162float(g2[(size_t)u2 * 16 + c]);
            float f3 = __bfloat162float(g2[(size_t)u3 * 16 + c]);
            acc += (f0 + f1) + (f2 + f3);
        }
        for (; j + 8 <= cnt; j += 8) {
            unsigned u0 = csr_src[start + j];
            unsigned u1 = csr_src[start + j + 4];
            float f0 = __bfloat162float(g2[(size_t)u0 * 16 + c]);
            float f1 = __bfloat162float(g2[(size_t)u1 * 16 + c]);
            acc += f0 + f1;
        }
        for (; j < cnt; j += 4) {
            unsigned u = csr_src[start + j];
            acc += __bfloat162float(g2[(size_t)u * 16 + c]);
        }
        acc += __shfl_xor(acc, 16, 64);
        acc += __shfl_xor(acc, 32, 64);
        if (jg == 0) out[(size_t)v * 16 + c] = dinv[v] * acc + b2[c];
    }
}

extern "C" void kernel_launch(void* const* d_in, const int* in_sizes, int n_in,
                              void* d_out, int out_size, void* d_ws, size_t ws_size,
                              hipStream_t stream) {
    const float* x     = (const float*)d_in[0];
    const int*   ei    = (const int*)d_in[1];
    const float* W1    = (const float*)d_in[2];
    const float* b1    = (const float*)d_in[3];
    const float* gamma = (const float*)d_in[4];
    const float* beta  = (const float*)d_in[5];
    const float* W2    = (const float*)d_in[6];
    const float* b2    = (const float*)d_in[7];
    float* out = (float*)d_out;

    int n = in_sizes[0] / 64;
    int E = in_sizes[1] / 2;
    const int* esrc = ei;
    const int* edst = ei + E;
    int nb = (n + (1 << NB_SHIFT) - 1) >> NB_SHIFT;   // 196 for n=100000 (<=256)

    char* ws = (char*)d_ws;
    size_t off = 0;
    auto alloc = [&](size_t bytes) {
        size_t o = off;
        off += (bytes + 255) & ~(size_t)255;
        return o;
    };
    unsigned* deg       = (unsigned*)(ws + alloc((size_t)n * 4));
    unsigned* row_start = (unsigned*)(ws + alloc((size_t)n * 4));
    float*    dinv      = (float*)(ws + alloc((size_t)n * 4));
    unsigned* csr_src   = (unsigned*)(ws + alloc((size_t)E * 4));
    __hip_bfloat16* g1  = (__hip_bfloat16*)(ws + alloc((size_t)n * 64 * 2));
    // union region: part (E*4, dead after k_bcsr) aliases h1p (n*64*4, born in k_agg1)
    size_t uoff = alloc((((size_t)E * 4) > ((size_t)n * 64 * 4)) ? (size_t)E * 4
                                                                 : (size_t)n * 64 * 4);
    unsigned* part      = (unsigned*)(ws + uoff);
    float*    h1p       = (float*)(ws + uoff);
    __hip_bfloat16* g2  = (__hip_bfloat16*)(ws + alloc((size_t)n * 16 * 2));
    // bn_part (8KB) + cursor_within (1KB) contiguous -> single memset
    double*   bn_part   = (double*)(ws + alloc(8 * 128 * 8));          // 8192B
    unsigned* cursor_w  = (unsigned*)(ws + alloc(256 * 4));            // 1024B
    unsigned* bstart    = (unsigned*)(ws + alloc(256 * 4));
    unsigned* resv      = (unsigned*)(ws + alloc((size_t)PB * 256 * 4));

    hipMemsetAsync(bn_part, 0, 8 * 128 * 8 + 256 * 4, stream);

    k_hist<<<PB, 256, 0, stream>>>(edst, E, nb, cursor_w, resv);
    k_bstart<<<1, 256, 0, stream>>>(cursor_w, nb, bstart);
    k_part<<<PB, 256, 0, stream>>>(esrc, edst, E, nb, resv, bstart, part);
    k_bcsr<<<nb, 256, 0, stream>>>(part, bstart, cursor_w, n, deg, row_start, dinv, csr_src);
    k_gemm1<<<512, 256, 0, stream>>>(x, W1, dinv, n, g1);
    k_agg1<<<2048, 256, 0, stream>>>(g1, row_start, deg, csr_src, dinv, b1, n, h1p, bn_part);
    k_bn_gemm2<<<512, 256, 0, stream>>>(h1p, W2, bn_part, gamma, beta, dinv, n, g2);
    k_agg2<<<2048, 256, 0, stream>>>(g2, row_start, deg, csr_src, dinv, b2, n, out);
}